// Round 2
// baseline (83.134 us; speedup 1.0000x reference)
//
#include <hip/hip_runtime.h>

// LengthRegulator: out[b, t, :] = phoneme[b, idx[b,t], :]
// idx[b,t] = searchsorted(inclusive_cumsum(durations[b]), t, side='right').
// Shapes fixed: B=16, N=256, D=512, T=2048. fp32 in/out.
//
// R1 -> R2: replace 16-barrier Hillis-Steele LDS scan with a register-only
// __shfl_up wave scan (6 steps) + single cross-wave combine (3 barriers
// total), and use int32 addressing throughout. Store phase unchanged
// (fully coalesced float4 rows, 2 rows per 256-thread iteration).

constexpr int B = 16;
constexpr int N = 256;    // tokens per batch (== block size)
constexpr int D = 512;    // feature dim -> 128 float4 per row
constexpr int T = 2048;   // output frames per batch

constexpr int BLOCKS_PER_B = 128;                  // blocks per batch
constexpr int FPB = T / BLOCKS_PER_B;              // 16 frames per block
constexpr int VPR = D / 4;                         // 128 float4 per row

__global__ __launch_bounds__(256) void lenreg_kernel(
    const float4* __restrict__ ph4,      // (B, N, D/4)
    const int*    __restrict__ durations,// (B, N)
    float4*       __restrict__ out4)     // (B, T, D/4)
{
    __shared__ int ends[N];     // inclusive cumsum of durations[b,:]
    __shared__ int wsum[4];     // per-wave totals
    __shared__ int fidx[FPB];   // token index per frame in this chunk

    const int b     = blockIdx.x >> 7;        // / BLOCKS_PER_B
    const int chunk = blockIdx.x & (BLOCKS_PER_B - 1);
    const int tid   = threadIdx.x;
    const int lane  = tid & 63;
    const int wid   = tid >> 6;

    // --- (a) inclusive prefix sum: register wave-scan, no barriers inside
    int v = durations[b * N + tid];
    #pragma unroll
    for (int off = 1; off < 64; off <<= 1) {
        int u = __shfl_up(v, off, 64);
        if (lane >= off) v += u;
    }
    if (lane == 63) wsum[wid] = v;
    __syncthreads();
    int prefix = 0;
    #pragma unroll
    for (int w = 0; w < 3; ++w)
        if (w < wid) prefix += wsum[w];
    ends[tid] = v + prefix;
    __syncthreads();

    // --- (b) token index for each of this block's 16 frames
    const int f0 = chunk * FPB;
    if (tid < FPB) {
        const int t = f0 + tid;
        int lo = 0, hi = N;         // first n with ends[n] > t
        while (lo < hi) {
            const int mid = (lo + hi) >> 1;
            if (ends[mid] > t) hi = mid; else lo = mid + 1;
        }
        fidx[tid] = (lo < N - 1) ? lo : (N - 1);
    }
    __syncthreads();

    // --- (c) stream 16 rows, 2 rows per iteration (128 float4 lanes/row)
    const int l    = tid & (VPR - 1);   // 0..127
    const int half = tid >> 7;          // 0 or 1
    const int outbase = (b * T + f0) * VPR;   // max ~4.2M, fits int32
    const int phbase  = b * N * VPR;
    #pragma unroll
    for (int i = 0; i < FPB / 2; ++i) {
        const int r     = i * 2 + half;
        const int token = fidx[r];
        out4[outbase + r * VPR + l] = ph4[phbase + token * VPR + l];
    }
}

extern "C" void kernel_launch(void* const* d_in, const int* in_sizes, int n_in,
                              void* d_out, int out_size, void* d_ws, size_t ws_size,
                              hipStream_t stream) {
    const float4* phoneme   = (const float4*)d_in[0];
    const int*    durations = (const int*)d_in[1];
    float4*       out       = (float4*)d_out;

    lenreg_kernel<<<B * BLOCKS_PER_B, 256, 0, stream>>>(phoneme, durations, out);
}